// Round 10
// baseline (173.500 us; speedup 1.0000x reference)
//
#include <hip/hip_runtime.h>

// ---------------------------------------------------------------------------
// StandardMultiHeadAttention: B=2, S=2048, D=1024, H=16, Dh=64, causal.
// fp32->f16 convert -> QKV GEMM (XCD-partitioned, LDS XOR-swizzled) ->
// flash attention (64 q-rows/block, 4-way KV split) -> output GEMM
// (XCD-partitioned, LDS XOR-swizzled).
//
// Workspace (48 MB):
//   [0,8M)    xb : x f16 [4096,1024]
//   [8M,16M)  wb : Wq,Wk,Wv,Wo f16 (row=out, K-major)
//   [16M,24M) QF : Q frag-major (pre-scaled by 0.125*log2e)
//   [24M,32M) KF : K frag-major (tile-contiguous, 2048 halfs / 32-row tile)
//   [32M,40M) VF : V^T frag-major (same tiling)
//   [40M,48M) ob : attention output [B,S,1024] f16
//
// R22. R21 confirmed the attn path model (-7.7us): attn = F + P*c, c~0.47us,
// F~25us; further path halving buys ~4us. New target: GEMM LDS reads.
// As/Ws [128][32] halfs: fragment ds_read_b128 at (base+ln, quad*16B) puts
// the wave on only 8/32 banks (bank-quad = (row&1, quad)) -> 8-way conflict
// (~2.9x, m136). Per CU: 3 blk x 16 Kstep x 16 reads x 1KB at ~44B/cyc
// ~ 30us = the whole qkv duration. Fix (T2, both-sides rule): col-group
// swizzle g' = g ^ ((row>>1)&3). Write via pre-swizzled GLOBAL source col
// (scol = ((l&3)^((l>>3)&3))*8; global_load_lds dest stays linear; 64B-
// window permutation keeps coalescing). Read at quad ^ ((ln>>1)&3) (row
// bases are multiples of 16). Bank spread now uniform (2 lanes/bank=free).
// Applied to qkv + out GEMMs; attn (R21) and cvt untouched.
// ---------------------------------------------------------------------------

typedef _Float16 f16x8 __attribute__((ext_vector_type(8)));
typedef _Float16 f16x4 __attribute__((ext_vector_type(4)));
typedef _Float16 f16x2 __attribute__((ext_vector_type(2)));
typedef float f32x4 __attribute__((ext_vector_type(4)));

#define S_  2048
#define DM  1024
#define NH  16
#define DH  64

__device__ __forceinline__ void gload_lds16(const void* g, void* s) {
  __builtin_amdgcn_global_load_lds(
      (const __attribute__((address_space(1))) void*)g,
      (__attribute__((address_space(3))) void*)s, 16, 0, 0);
}

__device__ __forceinline__ f16x2 pkrtz(float a, float b) {
  return __builtin_bit_cast(f16x2, __builtin_amdgcn_cvt_pkrtz(a, b));
}

// ----------------------------- convert kernel ------------------------------
// blocks [0,4096): x -> xb ; blocks [4096,8192): Wq..Wo -> wb

__global__ void cvt_all_kernel(const float* __restrict__ x,
                               const float* __restrict__ w0,
                               const float* __restrict__ w1,
                               const float* __restrict__ w2,
                               const float* __restrict__ w3,
                               _Float16* __restrict__ xb,
                               _Float16* __restrict__ wb) {
  const int bid = blockIdx.x;
  const float* src;
  _Float16* dst;
  int idx;
  if (bid < 4096) {
    src = x; dst = xb; idx = bid * 256 + threadIdx.x;
  } else {
    const int j = bid - 4096;
    const int y = j >> 10;
    src = (y == 0) ? w0 : (y == 1) ? w1 : (y == 2) ? w2 : w3;
    dst = wb + (size_t)y * (DM * DM);
    idx = (j & 1023) * 256 + threadIdx.x;
  }
  const float4 v = ((const float4*)src)[idx];
  f16x4 h;
  h[0] = (_Float16)v.x; h[1] = (_Float16)v.y;
  h[2] = (_Float16)v.z; h[3] = (_Float16)v.w;
  ((f16x4*)dst)[idx] = h;
}

// ---------------- QKV GEMM (BK=64, 2 slabs, XCD-partitioned) ----------------
// LDS col-group XOR swizzle: physical group = logical ^ ((row>>1)&3).
// 1-D grid of 768. Decode: xcd = i&7, t = i>>3 (0..95):
//   m-panel = xcd*4 + (t&3); u = t>>2: n-panel = u&7, z = u>>3.
// z=0: Q (bias, *0.125*log2e, QF layout); z=1: K (KF); z=2: V (VF)

__global__ __launch_bounds__(256, 3) void gemm_qkv_kernel(
    const _Float16* __restrict__ xb, const _Float16* __restrict__ wb,
    const float* __restrict__ bq, const float* __restrict__ bk,
    const float* __restrict__ bv, _Float16* __restrict__ qkv)
{
  __shared__ _Float16 As[2][128 * 32];   // slab h: k in [k0+32h, k0+32h+32)
  __shared__ _Float16 Ws[2][128 * 32];

  const int i = blockIdx.x;
  const int xcd = i & 7;
  const int tt = i >> 3;                 // 0..95
  const int mp = xcd * 4 + (tt & 3);     // m-panel 0..31
  const int u = tt >> 2;                 // 0..23
  const int np = u & 7;                  // n-panel 0..7
  const int z = u >> 3;                  // projection 0..2

  const _Float16* W = wb + (size_t)z * (DM * DM);
  const float* bias = (z == 0) ? bq : ((z == 1) ? bk : bv);
  _Float16* out = qkv + (size_t)z * 4194304;

  const f32x4 z4 = {0.f, 0.f, 0.f, 0.f};
  f32x4 acc[4][4];
#pragma unroll
  for (int mi = 0; mi < 4; ++mi)
#pragma unroll
    for (int ni = 0; ni < 4; ++ni) acc[mi][ni] = z4;

  const int m0 = mp * 128, n0 = np * 128;
  const int t = threadIdx.x;
  const int w = t >> 6, l = t & 63;
  const int quad = l >> 4, ln = l & 15;
  const int wm = (w >> 1) << 6, wn = (w & 1) << 6;
  const int srow = l >> 2;
  // pre-swizzled global source col-group: lane's LDS slot (row=l>>2, g=l&3)
  // must hold global group g ^ ((row>>1)&3) = (l&3) ^ ((l>>3)&3).
  const int scol = (((l & 3) ^ ((l >> 3) & 3))) << 3;
  const int rsw = (ln >> 1) & 3;         // read-side swizzle term

  for (int k0 = 0; k0 < DM; k0 += 64) {
#pragma unroll
    for (int h = 0; h < 2; ++h)
#pragma unroll
      for (int i2 = 0; i2 < 2; ++i2) {
        const int ra = w * 32 + i2 * 16;
        gload_lds16(&xb[(size_t)(m0 + ra + srow) * DM + k0 + h * 32 + scol],
                    &As[h][ra * 32]);
        gload_lds16(&W[(size_t)(n0 + ra + srow) * DM + k0 + h * 32 + scol],
                    &Ws[h][ra * 32]);
      }
    __syncthreads();

#pragma unroll
    for (int h = 0; h < 2; ++h) {
      f16x8 af[4], bf[4];
#pragma unroll
      for (int mi = 0; mi < 4; ++mi)
        af[mi] = *(const f16x8*)
            &As[h][(wm + mi * 16 + ln) * 32 + (quad ^ rsw) * 8];
#pragma unroll
      for (int ni = 0; ni < 4; ++ni)
        bf[ni] = *(const f16x8*)
            &Ws[h][(wn + ni * 16 + ln) * 32 + (quad ^ rsw) * 8];
#pragma unroll
      for (int mi = 0; mi < 4; ++mi)
#pragma unroll
        for (int ni = 0; ni < 4; ++ni)
          acc[mi][ni] = __builtin_amdgcn_mfma_f32_16x16x32_f16(
              af[mi], bf[ni], acc[mi][ni], 0, 0, 0);
    }
    __syncthreads();
  }

  // fold 1/sqrt(Dh) * log2(e) into Q so attention uses exp2
  const float scale = (z == 0) ? 0.18033688f : 1.0f;

#pragma unroll
  for (int ni = 0; ni < 4; ++ni) {
    const int c = n0 + wn + ni * 16 + ln;
    const float bias_c = bias[c];
    const int h = c >> 6, d = c & 63;
#pragma unroll
    for (int mi = 0; mi < 4; ++mi) {
      const int mb = m0 + wm + mi * 16 + quad * 4;
#pragma unroll
      for (int r = 0; r < 4; ++r) {
        const int mg = mb + r;
        const int b = mg >> 11, s = mg & 2047;
        const int bh = b * NH + h;
        const float v = (acc[mi][ni][r] + bias_c) * scale;
        size_t idx;
        if (z == 2)
          idx = (size_t)bh * 131072 + (s >> 5) * 2048 + (d >> 4) * 512 +
                ((s >> 3) & 3) * 128 + (d & 15) * 8 + (s & 7);
        else
          idx = (size_t)bh * 131072 + (s >> 4) * 1024 + (d >> 5) * 512 +
                ((d >> 3) & 3) * 128 + (s & 15) * 8 + (d & 7);
        out[idx] = (_Float16)v;
      }
    }
  }
}

// -------- output GEMM (BK=64 two-slab, 128x64 tile, XCD-partitioned) --------
// Same LDS XOR swizzle. 1-D grid of 512: xcd = i&7, t = i>>3 (0..63):
//   m-panel = xcd*4 + (t&3); n-panel = t>>2 (0..15).

__global__ __launch_bounds__(256, 2) void gemm_out_kernel(
    const _Float16* __restrict__ ob, const _Float16* __restrict__ wo,
    const float* __restrict__ bo, float* __restrict__ out)
{
  __shared__ _Float16 As[2][128 * 32];
  __shared__ _Float16 Ws[2][64 * 32];

  const int i = blockIdx.x;
  const int xcd = i & 7;
  const int tt = i >> 3;                 // 0..63
  const int mp = xcd * 4 + (tt & 3);     // m-panel 0..31
  const int np = tt >> 2;                // n-panel 0..15

  const f32x4 z4 = {0.f, 0.f, 0.f, 0.f};
  f32x4 acc[2][4];
#pragma unroll
  for (int mi = 0; mi < 2; ++mi)
#pragma unroll
    for (int ni = 0; ni < 4; ++ni) acc[mi][ni] = z4;

  const int m0 = mp * 128, n0 = np * 64;
  const int t = threadIdx.x;
  const int w = t >> 6, l = t & 63;
  const int quad = l >> 4, ln = l & 15;
  const int srow = l >> 2;
  const int scol = (((l & 3) ^ ((l >> 3) & 3))) << 3;
  const int rsw = (ln >> 1) & 3;

  for (int k0 = 0; k0 < DM; k0 += 64) {
#pragma unroll
    for (int h = 0; h < 2; ++h) {
#pragma unroll
      for (int i2 = 0; i2 < 2; ++i2) {
        const int ra = w * 32 + i2 * 16;
        gload_lds16(&ob[(size_t)(m0 + ra + srow) * DM + k0 + h * 32 + scol],
                    &As[h][ra * 32]);
      }
      gload_lds16(&wo[(size_t)(n0 + w * 16 + srow) * DM + k0 + h * 32 + scol],
                  &Ws[h][w * 16 * 32]);
    }
    __syncthreads();

#pragma unroll
    for (int h = 0; h < 2; ++h) {
      f16x8 af[2], bf[4];
#pragma unroll
      for (int mi = 0; mi < 2; ++mi)
        af[mi] = *(const f16x8*)
            &As[h][(w * 32 + mi * 16 + ln) * 32 + (quad ^ rsw) * 8];
#pragma unroll
      for (int ni = 0; ni < 4; ++ni)
        bf[ni] = *(const f16x8*)
            &Ws[h][(ni * 16 + ln) * 32 + (quad ^ rsw) * 8];
#pragma unroll
      for (int mi = 0; mi < 2; ++mi)
#pragma unroll
        for (int ni = 0; ni < 4; ++ni)
          acc[mi][ni] = __builtin_amdgcn_mfma_f32_16x16x32_f16(
              af[mi], bf[ni], acc[mi][ni], 0, 0, 0);
    }
    __syncthreads();
  }

#pragma unroll
  for (int ni = 0; ni < 4; ++ni) {
    const int c = n0 + ni * 16 + ln;
    const float bias_c = bo[c];
#pragma unroll
    for (int mi = 0; mi < 2; ++mi) {
      const int mb = m0 + w * 32 + mi * 16 + quad * 4;
#pragma unroll
      for (int r = 0; r < 4; ++r)
        out[(size_t)(mb + r) * DM + c] = acc[mi][ni][r] + bias_c;
    }
  }
}

// ---------------------------- flash attention ------------------------------
// R21: 1024 blocks x 4 waves (256 thr); block = (bh = i&31, qb = 31-(i>>5),
// 64 q-rows, longest first). Wave e takes kv tiles t == e (mod 4) ->
// critical path 16 serial tiles. Per tile: K,V global->reg, per q-subtile
// qs: 4 QK MFMA -> exp2+mask -> Ps (slot-swizzled) -> 4 PV MFMA. Merge
// tree: waves 1,3 write bufs; 0,2 add; 2 writes; 0 adds + outputs.

template <int MODE>   // 0: full | 1: diag(qs0,1)+full(qs2,3) | 2: skip+diag
__device__ __forceinline__ void tile64(
    const _Float16* __restrict__ kb_, const _Float16* __restrict__ vb_,
    int t, const f16x8 (&qf)[4][2], f32x4 (&oacc)[4][4], float (&l_i)[4],
    _Float16* Ps, int quad, int ln, int l)
{
  f16x8 kr[4], vr[4];
#pragma unroll
  for (int ii = 0; ii < 4; ++ii)
    kr[ii] = *(const f16x8*)(kb_ + (size_t)t * 2048 + ii * 512 + l * 8);
#pragma unroll
  for (int ii = 0; ii < 4; ++ii)
    vr[ii] = *(const f16x8*)(vb_ + (size_t)t * 2048 + ii * 512 + l * 8);

  const f32x4 z4 = {0.f, 0.f, 0.f, 0.f};
#pragma unroll
  for (int qs = 0; qs < 4; ++qs) {
    if (MODE == 2 && qs < 2) continue;   // empty sub-tiles above diagonal

    f32x4 sacc[2];
    sacc[0] = z4; sacc[1] = z4;
#pragma unroll
    for (int ks = 0; ks < 2; ++ks)
#pragma unroll
      for (int mi = 0; mi < 2; ++mi)
        sacc[mi] = __builtin_amdgcn_mfma_f32_16x16x32_f16(
            kr[mi * 2 + ks], qf[qs][ks], sacc[mi], 0, 0, 0);

    const bool DG = (MODE == 1 && qs < 2) || (MODE == 2);
    const int hq = ((MODE == 1) ? qs : (qs - 2)) << 4;

    float rs = 0.f;
#pragma unroll
    for (int mi = 0; mi < 2; ++mi) {
      float p[4];
#pragma unroll
      for (int r = 0; r < 4; ++r) {
        p[r] = __builtin_amdgcn_exp2f(sacc[mi][r]);
        if (DG && (mi * 16 + quad * 4 + r > hq + ln)) p[r] = 0.f;
        rs += p[r];
      }
      const f16x2 lo = pkrtz(p[0], p[1]);
      const f16x2 hi = pkrtz(p[2], p[3]);
      const f16x4 pk = __builtin_shufflevector(lo, hi, 0, 1, 2, 3);
      // slot swizzle: stride 64 halfs (128 B) -> row drops out of bank index
      const int slot = ((mi * 4 + quad) + 2 * ln) & 15;
      *(f16x4*)&Ps[ln * 64 + slot * 4] = pk;
    }
    l_i[qs] += rs;

    const int slot2 = ((quad * 2) + 2 * ln) & 15;  // even -> 16B aligned
    const f16x8 pb = *(const f16x8*)&Ps[ln * 64 + slot2 * 4];

#pragma unroll
    for (int di = 0; di < 4; ++di)
      oacc[qs][di] = __builtin_amdgcn_mfma_f32_16x16x32_f16(
          vr[di], pb, oacc[qs][di], 0, 0, 0);
  }
}

__global__ __launch_bounds__(256, 3) void attn_kernel(
    const _Float16* __restrict__ QF, const _Float16* __restrict__ KF,
    const _Float16* __restrict__ VF, _Float16* __restrict__ Ob)
{
  __shared__ _Float16 Ps[4][1024];      // 8 KB (2 KB per wave)
  __shared__ float mrgO[2][4][1024];    // 32 KB: [buf][qs][di*256 + l*4]
  __shared__ float mrgL[2][4][64];      // 2 KB

  const int i = blockIdx.x;
  const int bh = i & 31;                // heads XCD-local
  const int qb = 31 - (i >> 5);         // 64-row q-block; longest first

  const int tid = threadIdx.x;
  const int e = tid >> 6, l = tid & 63; // e = kv residue class (mod 4)
  const int quad = l >> 4, ln = l & 15;

  const _Float16* qb_ = QF + (size_t)bh * 131072;
  const _Float16* kb_ = KF + (size_t)bh * 131072;
  const _Float16* vb_ = VF + (size_t)bh * 131072;
  _Float16* psw = &Ps[e][0];
  const int bidx = bh >> 4, hh = bh & 15;

  // Q fragments for rows [qb*64, +64): row-block rb = 4*qb + qs
  f16x8 qf[4][2];
#pragma unroll
  for (int qs = 0; qs < 4; ++qs)
#pragma unroll
    for (int ks = 0; ks < 2; ++ks)
      qf[qs][ks] = *(const f16x8*)
          (qb_ + (size_t)((4 * qb + qs) * 2 + ks) * 512 + l * 8);

  const f32x4 z4 = {0.f, 0.f, 0.f, 0.f};
  f32x4 oacc[4][4];
#pragma unroll
  for (int qs = 0; qs < 4; ++qs)
#pragma unroll
    for (int di = 0; di < 4; ++di) oacc[qs][di] = z4;
  float l_i[4] = {0.f, 0.f, 0.f, 0.f};

  // full tiles in this wave's residue class
  for (int t = e; t < 2 * qb; t += 4)
    tile64<0>(kb_, vb_, t, qf, oacc, l_i, psw, quad, ln, l);
  // diagonal tiles 2qb (MODE 1) and 2qb+1 (MODE 2), by residue class
  if (((2 * qb) & 3) == e)
    tile64<1>(kb_, vb_, 2 * qb, qf, oacc, l_i, psw, quad, ln, l);
  if (((2 * qb + 1) & 3) == e)
    tile64<2>(kb_, vb_, 2 * qb + 1, qf, oacc, l_i, psw, quad, ln, l);

  // merge round 1: waves 1,3 write bufs 0,1; waves 0,2 add
  if (e & 1) {
    const int buf = e >> 1;
#pragma unroll
    for (int qs = 0; qs < 4; ++qs) {
#pragma unroll
      for (int di = 0; di < 4; ++di)
        *(f32x4*)&mrgO[buf][qs][di * 256 + l * 4] = oacc[qs][di];
      mrgL[buf][qs][l] = l_i[qs];
    }
  }
  __syncthreads();
  if (!(e & 1)) {
    const int buf = e >> 1;
#pragma unroll
    for (int qs = 0; qs < 4; ++qs) {
#pragma unroll
      for (int di = 0; di < 4; ++di)
        oacc[qs][di] += *(const f32x4*)&mrgO[buf][qs][di * 256 + l * 4];
      l_i[qs] += mrgL[buf][qs][l];
    }
  }
  __syncthreads();   // WAR: round-1 reads done before buf 0 reuse
  // merge round 2: wave 2 writes buf 0; wave 0 adds + outputs
  if (e == 2) {
#pragma unroll
    for (int qs = 0; qs < 4; ++qs) {
#pragma unroll
      for (int di = 0; di < 4; ++di)
        *(f32x4*)&mrgO[0][qs][di * 256 + l * 4] = oacc[qs][di];
      mrgL[0][qs][l] = l_i[qs];
    }
  }
  __syncthreads();
  if (e == 0) {
#pragma unroll
    for (int qs = 0; qs < 4; ++qs) {
#pragma unroll
      for (int di = 0; di < 4; ++di)
        oacc[qs][di] += *(const f32x4*)&mrgO[0][qs][di * 256 + l * 4];
      float li = l_i[qs] + mrgL[0][qs][l];
      li += __shfl_xor(li, 16);
      li += __shfl_xor(li, 32);
      const float inv = 1.0f / li;

      const int q = qb * 64 + qs * 16 + ln;
      _Float16* orow = Ob + (size_t)(bidx * S_ + q) * DM + hh * DH + quad * 4;
#pragma unroll
      for (int di = 0; di < 4; ++di) {
        f16x4 o4;
#pragma unroll
        for (int r = 0; r < 4; ++r)
          o4[r] = (_Float16)(oacc[qs][di][r] * inv);
        *(f16x4*)(orow + di * 16) = o4;
      }
    }
  }
}

// ------------------------------- launcher ----------------------------------

extern "C" void kernel_launch(void* const* d_in, const int* in_sizes, int n_in,
                              void* d_out, int out_size, void* d_ws, size_t ws_size,
                              hipStream_t stream) {
  (void)in_sizes; (void)n_in; (void)out_size; (void)ws_size;
  const float* x  = (const float*)d_in[0];
  const float* Wq = (const float*)d_in[1];
  const float* bq = (const float*)d_in[2];
  const float* Wk = (const float*)d_in[3];
  const float* bk = (const float*)d_in[4];
  const float* Wv = (const float*)d_in[5];
  const float* bv = (const float*)d_in[6];
  const float* Wo = (const float*)d_in[7];
  const float* bo = (const float*)d_in[8];

  char* ws = (char*)d_ws;
  _Float16* xb  = (_Float16*)(ws);                      // 8 MB
  _Float16* wb  = (_Float16*)(ws + (8u << 20));         // 4 x 2 MB
  _Float16* qkv = (_Float16*)(ws + (16u << 20));        // QF,KF,VF 8 MB each
  _Float16* ob  = (_Float16*)(ws + (40u << 20));        // 8 MB

  cvt_all_kernel<<<dim3(8192), dim3(256), 0, stream>>>(x, Wq, Wk, Wv, Wo, xb, wb);
  gemm_qkv_kernel<<<dim3(768), dim3(256), 0, stream>>>(xb, wb, bq, bk, bv, qkv);
  attn_kernel<<<dim3(1024), dim3(256), 0, stream>>>(
      qkv, qkv + 4194304, qkv + 2 * 4194304, ob);
  gemm_out_kernel<<<dim3(512), dim3(256), 0, stream>>>(
      ob, wb + (size_t)3 * DM * DM, bo, (float*)d_out);
}

// Round 11
// 167.582 us; speedup vs baseline: 1.0353x; 1.0353x over previous
//
#include <hip/hip_runtime.h>

// ---------------------------------------------------------------------------
// StandardMultiHeadAttention: B=2, S=2048, D=1024, H=16, Dh=64, causal.
// fp32->f16 convert -> QKV GEMM (XCD-partitioned) -> flash attention
// (64 q-rows/block, 4-way KV split, K/V tile prefetch) -> output GEMM
// (XCD-partitioned).
//
// Workspace (48 MB):
//   [0,8M)    xb : x f16 [4096,1024]
//   [8M,16M)  wb : Wq,Wk,Wv,Wo f16 (row=out, K-major)
//   [16M,24M) QF : Q frag-major (pre-scaled by 0.125*log2e)
//   [24M,32M) KF : K frag-major (tile-contiguous, 2048 halfs / 32-row tile)
//   [32M,40M) VF : V^T frag-major (same tiling)
//   [40M,48M) ob : attention output [B,S,1024] f16
//
// R23. R22 swizzle was NULL (+1us, within noise) -> GEMM LDS conflicts not
// the limiting term (T2 regime gate: 2-phase staging path hides them);
// reverted. Confirmed model: attn = F(~25us) + path*c, c ~1130 cyc =
// ~300 naked K/V L2-load wait + ~830 compute. R23 removes the load term:
// prefetch tile t+4's K/V into regs while computing tile t (ILP across the
// wave's own serial chain -- R13 tried this at path 64 where the path
// didn't matter; at path 16 the chain IS the makespan). +64 VGPR ->
// launch_bounds(256,2) (cap 256, ~200 used). Occupancy 3->2 blocks/CU:
// attn shown occupancy-insensitive (R16/R18); longest-first backfills.
// ---------------------------------------------------------------------------

typedef _Float16 f16x8 __attribute__((ext_vector_type(8)));
typedef _Float16 f16x4 __attribute__((ext_vector_type(4)));
typedef _Float16 f16x2 __attribute__((ext_vector_type(2)));
typedef float f32x4 __attribute__((ext_vector_type(4)));

#define S_  2048
#define DM  1024
#define NH  16
#define DH  64

__device__ __forceinline__ void gload_lds16(const void* g, void* s) {
  __builtin_amdgcn_global_load_lds(
      (const __attribute__((address_space(1))) void*)g,
      (__attribute__((address_space(3))) void*)s, 16, 0, 0);
}

__device__ __forceinline__ f16x2 pkrtz(float a, float b) {
  return __builtin_bit_cast(f16x2, __builtin_amdgcn_cvt_pkrtz(a, b));
}

// ----------------------------- convert kernel ------------------------------
// blocks [0,4096): x -> xb ; blocks [4096,8192): Wq..Wo -> wb

__global__ void cvt_all_kernel(const float* __restrict__ x,
                               const float* __restrict__ w0,
                               const float* __restrict__ w1,
                               const float* __restrict__ w2,
                               const float* __restrict__ w3,
                               _Float16* __restrict__ xb,
                               _Float16* __restrict__ wb) {
  const int bid = blockIdx.x;
  const float* src;
  _Float16* dst;
  int idx;
  if (bid < 4096) {
    src = x; dst = xb; idx = bid * 256 + threadIdx.x;
  } else {
    const int j = bid - 4096;
    const int y = j >> 10;
    src = (y == 0) ? w0 : (y == 1) ? w1 : (y == 2) ? w2 : w3;
    dst = wb + (size_t)y * (DM * DM);
    idx = (j & 1023) * 256 + threadIdx.x;
  }
  const float4 v = ((const float4*)src)[idx];
  f16x4 h;
  h[0] = (_Float16)v.x; h[1] = (_Float16)v.y;
  h[2] = (_Float16)v.z; h[3] = (_Float16)v.w;
  ((f16x4*)dst)[idx] = h;
}

// ---------------- QKV GEMM (BK=64, 2 slabs, XCD-partitioned) ----------------
// 1-D grid of 768. Decode: xcd = i&7, t = i>>3 (0..95):
//   m-panel = xcd*4 + (t&3); u = t>>2: n-panel = u&7, z = u>>3.
// z=0: Q (bias, *0.125*log2e, QF layout); z=1: K (KF); z=2: V (VF)

__global__ __launch_bounds__(256, 3) void gemm_qkv_kernel(
    const _Float16* __restrict__ xb, const _Float16* __restrict__ wb,
    const float* __restrict__ bq, const float* __restrict__ bk,
    const float* __restrict__ bv, _Float16* __restrict__ qkv)
{
  __shared__ _Float16 As[2][128 * 32];   // slab h: k in [k0+32h, k0+32h+32)
  __shared__ _Float16 Ws[2][128 * 32];

  const int i = blockIdx.x;
  const int xcd = i & 7;
  const int tt = i >> 3;                 // 0..95
  const int mp = xcd * 4 + (tt & 3);     // m-panel 0..31
  const int u = tt >> 2;                 // 0..23
  const int np = u & 7;                  // n-panel 0..7
  const int z = u >> 3;                  // projection 0..2

  const _Float16* W = wb + (size_t)z * (DM * DM);
  const float* bias = (z == 0) ? bq : ((z == 1) ? bk : bv);
  _Float16* out = qkv + (size_t)z * 4194304;

  const f32x4 z4 = {0.f, 0.f, 0.f, 0.f};
  f32x4 acc[4][4];
#pragma unroll
  for (int mi = 0; mi < 4; ++mi)
#pragma unroll
    for (int ni = 0; ni < 4; ++ni) acc[mi][ni] = z4;

  const int m0 = mp * 128, n0 = np * 128;
  const int t = threadIdx.x;
  const int w = t >> 6, l = t & 63;
  const int quad = l >> 4, ln = l & 15;
  const int wm = (w >> 1) << 6, wn = (w & 1) << 6;
  const int srow = l >> 2, scol = (l & 3) << 3;

  for (int k0 = 0; k0 < DM; k0 += 64) {
#pragma unroll
    for (int h = 0; h < 2; ++h)
#pragma unroll
      for (int i2 = 0; i2 < 2; ++i2) {
        const int ra = w * 32 + i2 * 16;
        gload_lds16(&xb[(size_t)(m0 + ra + srow) * DM + k0 + h * 32 + scol],
                    &As[h][ra * 32]);
        gload_lds16(&W[(size_t)(n0 + ra + srow) * DM + k0 + h * 32 + scol],
                    &Ws[h][ra * 32]);
      }
    __syncthreads();

#pragma unroll
    for (int h = 0; h < 2; ++h) {
      f16x8 af[4], bf[4];
#pragma unroll
      for (int mi = 0; mi < 4; ++mi)
        af[mi] = *(const f16x8*)&As[h][(wm + mi * 16 + ln) * 32 + quad * 8];
#pragma unroll
      for (int ni = 0; ni < 4; ++ni)
        bf[ni] = *(const f16x8*)&Ws[h][(wn + ni * 16 + ln) * 32 + quad * 8];
#pragma unroll
      for (int mi = 0; mi < 4; ++mi)
#pragma unroll
        for (int ni = 0; ni < 4; ++ni)
          acc[mi][ni] = __builtin_amdgcn_mfma_f32_16x16x32_f16(
              af[mi], bf[ni], acc[mi][ni], 0, 0, 0);
    }
    __syncthreads();
  }

  // fold 1/sqrt(Dh) * log2(e) into Q so attention uses exp2
  const float scale = (z == 0) ? 0.18033688f : 1.0f;

#pragma unroll
  for (int ni = 0; ni < 4; ++ni) {
    const int c = n0 + wn + ni * 16 + ln;
    const float bias_c = bias[c];
    const int h = c >> 6, d = c & 63;
#pragma unroll
    for (int mi = 0; mi < 4; ++mi) {
      const int mb = m0 + wm + mi * 16 + quad * 4;
#pragma unroll
      for (int r = 0; r < 4; ++r) {
        const int mg = mb + r;
        const int b = mg >> 11, s = mg & 2047;
        const int bh = b * NH + h;
        const float v = (acc[mi][ni][r] + bias_c) * scale;
        size_t idx;
        if (z == 2)
          idx = (size_t)bh * 131072 + (s >> 5) * 2048 + (d >> 4) * 512 +
                ((s >> 3) & 3) * 128 + (d & 15) * 8 + (s & 7);
        else
          idx = (size_t)bh * 131072 + (s >> 4) * 1024 + (d >> 5) * 512 +
                ((d >> 3) & 3) * 128 + (s & 15) * 8 + (d & 7);
        out[idx] = (_Float16)v;
      }
    }
  }
}

// -------- output GEMM (BK=64 two-slab, 128x64 tile, XCD-partitioned) --------
// 1-D grid of 512. Decode: xcd = i&7, t = i>>3 (0..63):
//   m-panel = xcd*4 + (t&3); n-panel = t>>2 (0..15).

__global__ __launch_bounds__(256, 2) void gemm_out_kernel(
    const _Float16* __restrict__ ob, const _Float16* __restrict__ wo,
    const float* __restrict__ bo, float* __restrict__ out)
{
  __shared__ _Float16 As[2][128 * 32];
  __shared__ _Float16 Ws[2][64 * 32];

  const int i = blockIdx.x;
  const int xcd = i & 7;
  const int tt = i >> 3;                 // 0..63
  const int mp = xcd * 4 + (tt & 3);     // m-panel 0..31
  const int np = tt >> 2;                // n-panel 0..15

  const f32x4 z4 = {0.f, 0.f, 0.f, 0.f};
  f32x4 acc[2][4];
#pragma unroll
  for (int mi = 0; mi < 2; ++mi)
#pragma unroll
    for (int ni = 0; ni < 4; ++ni) acc[mi][ni] = z4;

  const int m0 = mp * 128, n0 = np * 64;
  const int t = threadIdx.x;
  const int w = t >> 6, l = t & 63;
  const int quad = l >> 4, ln = l & 15;
  const int srow = l >> 2, scol = (l & 3) << 3;

  for (int k0 = 0; k0 < DM; k0 += 64) {
#pragma unroll
    for (int h = 0; h < 2; ++h) {
#pragma unroll
      for (int i2 = 0; i2 < 2; ++i2) {
        const int ra = w * 32 + i2 * 16;
        gload_lds16(&ob[(size_t)(m0 + ra + srow) * DM + k0 + h * 32 + scol],
                    &As[h][ra * 32]);
      }
      gload_lds16(&wo[(size_t)(n0 + w * 16 + srow) * DM + k0 + h * 32 + scol],
                  &Ws[h][w * 16 * 32]);
    }
    __syncthreads();

#pragma unroll
    for (int h = 0; h < 2; ++h) {
      f16x8 af[2], bf[4];
#pragma unroll
      for (int mi = 0; mi < 2; ++mi)
        af[mi] = *(const f16x8*)&As[h][(w * 32 + mi * 16 + ln) * 32 + quad * 8];
#pragma unroll
      for (int ni = 0; ni < 4; ++ni)
        bf[ni] = *(const f16x8*)&Ws[h][(ni * 16 + ln) * 32 + quad * 8];
#pragma unroll
      for (int mi = 0; mi < 2; ++mi)
#pragma unroll
        for (int ni = 0; ni < 4; ++ni)
          acc[mi][ni] = __builtin_amdgcn_mfma_f32_16x16x32_f16(
              af[mi], bf[ni], acc[mi][ni], 0, 0, 0);
    }
    __syncthreads();
  }

#pragma unroll
  for (int ni = 0; ni < 4; ++ni) {
    const int c = n0 + ni * 16 + ln;
    const float bias_c = bo[c];
#pragma unroll
    for (int mi = 0; mi < 2; ++mi) {
      const int mb = m0 + w * 32 + mi * 16 + quad * 4;
#pragma unroll
      for (int r = 0; r < 4; ++r)
        out[(size_t)(mb + r) * DM + c] = acc[mi][ni][r] + bias_c;
    }
  }
}

// ---------------------------- flash attention ------------------------------
// R23: 1024 blocks x 4 waves (256 thr); block = (bh = i&31, qb = 31-(i>>5),
// 64 q-rows, longest first). Wave e takes kv tiles t == e (mod 4): path 16.
// Full-tile loop prefetches tile t+4's K/V into regs while computing tile t
// (removes the ~300-cyc load wait from the serial chain). Diag tiles loaded
// ad hoc (<=2/wave). Merge tree: waves 1,3 write bufs; 0,2 add; 2 writes;
// 0 adds + outputs. launch_bounds(256,2): ~200 VGPR, no spill.

__device__ __forceinline__ void ldkv(
    const _Float16* __restrict__ kb_, const _Float16* __restrict__ vb_,
    int t, int l, f16x8 (&kr)[4], f16x8 (&vr)[4])
{
#pragma unroll
  for (int ii = 0; ii < 4; ++ii)
    kr[ii] = *(const f16x8*)(kb_ + (size_t)t * 2048 + ii * 512 + l * 8);
#pragma unroll
  for (int ii = 0; ii < 4; ++ii)
    vr[ii] = *(const f16x8*)(vb_ + (size_t)t * 2048 + ii * 512 + l * 8);
}

template <int MODE>   // 0: full | 1: diag(qs0,1)+full(qs2,3) | 2: skip+diag
__device__ __forceinline__ void compute64(
    const f16x8 (&kr)[4], const f16x8 (&vr)[4],
    const f16x8 (&qf)[4][2], f32x4 (&oacc)[4][4], float (&l_i)[4],
    _Float16* Ps, int quad, int ln)
{
  const f32x4 z4 = {0.f, 0.f, 0.f, 0.f};
#pragma unroll
  for (int qs = 0; qs < 4; ++qs) {
    if (MODE == 2 && qs < 2) continue;   // empty sub-tiles above diagonal

    f32x4 sacc[2];
    sacc[0] = z4; sacc[1] = z4;
#pragma unroll
    for (int ks = 0; ks < 2; ++ks)
#pragma unroll
      for (int mi = 0; mi < 2; ++mi)
        sacc[mi] = __builtin_amdgcn_mfma_f32_16x16x32_f16(
            kr[mi * 2 + ks], qf[qs][ks], sacc[mi], 0, 0, 0);

    const bool DG = (MODE == 1 && qs < 2) || (MODE == 2);
    const int hq = ((MODE == 1) ? qs : (qs - 2)) << 4;

    float rs = 0.f;
#pragma unroll
    for (int mi = 0; mi < 2; ++mi) {
      float p[4];
#pragma unroll
      for (int r = 0; r < 4; ++r) {
        p[r] = __builtin_amdgcn_exp2f(sacc[mi][r]);
        if (DG && (mi * 16 + quad * 4 + r > hq + ln)) p[r] = 0.f;
        rs += p[r];
      }
      const f16x2 lo = pkrtz(p[0], p[1]);
      const f16x2 hi = pkrtz(p[2], p[3]);
      const f16x4 pk = __builtin_shufflevector(lo, hi, 0, 1, 2, 3);
      // slot swizzle: stride 64 halfs (128 B) -> row drops out of bank index
      const int slot = ((mi * 4 + quad) + 2 * ln) & 15;
      *(f16x4*)&Ps[ln * 64 + slot * 4] = pk;
    }
    l_i[qs] += rs;

    const int slot2 = ((quad * 2) + 2 * ln) & 15;  // even -> 16B aligned
    const f16x8 pb = *(const f16x8*)&Ps[ln * 64 + slot2 * 4];

#pragma unroll
    for (int di = 0; di < 4; ++di)
      oacc[qs][di] = __builtin_amdgcn_mfma_f32_16x16x32_f16(
          vr[di], pb, oacc[qs][di], 0, 0, 0);
  }
}

__global__ __launch_bounds__(256, 2) void attn_kernel(
    const _Float16* __restrict__ QF, const _Float16* __restrict__ KF,
    const _Float16* __restrict__ VF, _Float16* __restrict__ Ob)
{
  __shared__ _Float16 Ps[4][1024];      // 8 KB (2 KB per wave)
  __shared__ float mrgO[2][4][1024];    // 32 KB: [buf][qs][di*256 + l*4]
  __shared__ float mrgL[2][4][64];      // 2 KB

  const int i = blockIdx.x;
  const int bh = i & 31;                // heads XCD-local
  const int qb = 31 - (i >> 5);         // 64-row q-block; longest first

  const int tid = threadIdx.x;
  const int e = tid >> 6, l = tid & 63; // e = kv residue class (mod 4)
  const int quad = l >> 4, ln = l & 15;

  const _Float16* qb_ = QF + (size_t)bh * 131072;
  const _Float16* kb_ = KF + (size_t)bh * 131072;
  const _Float16* vb_ = VF + (size_t)bh * 131072;
  _Float16* psw = &Ps[e][0];
  const int bidx = bh >> 4, hh = bh & 15;

  // Q fragments for rows [qb*64, +64): row-block rb = 4*qb + qs
  f16x8 qf[4][2];
#pragma unroll
  for (int qs = 0; qs < 4; ++qs)
#pragma unroll
    for (int ks = 0; ks < 2; ++ks)
      qf[qs][ks] = *(const f16x8*)
          (qb_ + (size_t)((4 * qb + qs) * 2 + ks) * 512 + l * 8);

  const f32x4 z4 = {0.f, 0.f, 0.f, 0.f};
  f32x4 oacc[4][4];
#pragma unroll
  for (int qs = 0; qs < 4; ++qs)
#pragma unroll
    for (int di = 0; di < 4; ++di) oacc[qs][di] = z4;
  float l_i[4] = {0.f, 0.f, 0.f, 0.f};

  // full tiles in this wave's residue class, 1-tile K/V register prefetch
  f16x8 kr[4], vr[4];
  int t = e;
  if (t < 2 * qb) {
    ldkv(kb_, vb_, t, l, kr, vr);
    for (; t + 4 < 2 * qb; t += 4) {
      f16x8 kn[4], vn[4];
      ldkv(kb_, vb_, t + 4, l, kn, vn);
      compute64<0>(kr, vr, qf, oacc, l_i, psw, quad, ln);
#pragma unroll
      for (int ii = 0; ii < 4; ++ii) { kr[ii] = kn[ii]; vr[ii] = vn[ii]; }
    }
    compute64<0>(kr, vr, qf, oacc, l_i, psw, quad, ln);
  }
  // diagonal tiles 2qb (MODE 1) and 2qb+1 (MODE 2), by residue class
  if (((2 * qb) & 3) == e) {
    ldkv(kb_, vb_, 2 * qb, l, kr, vr);
    compute64<1>(kr, vr, qf, oacc, l_i, psw, quad, ln);
  }
  if (((2 * qb + 1) & 3) == e) {
    ldkv(kb_, vb_, 2 * qb + 1, l, kr, vr);
    compute64<2>(kr, vr, qf, oacc, l_i, psw, quad, ln);
  }

  // merge round 1: waves 1,3 write bufs 0,1; waves 0,2 add
  if (e & 1) {
    const int buf = e >> 1;
#pragma unroll
    for (int qs = 0; qs < 4; ++qs) {
#pragma unroll
      for (int di = 0; di < 4; ++di)
        *(f32x4*)&mrgO[buf][qs][di * 256 + l * 4] = oacc[qs][di];
      mrgL[buf][qs][l] = l_i[qs];
    }
  }
  __syncthreads();
  if (!(e & 1)) {
    const int buf = e >> 1;
#pragma unroll
    for (int qs = 0; qs < 4; ++qs) {
#pragma unroll
      for (int di = 0; di < 4; ++di)
        oacc[qs][di] += *(const f32x4*)&mrgO[buf][qs][di * 256 + l * 4];
      l_i[qs] += mrgL[buf][qs][l];
    }
  }
  __syncthreads();   // WAR: round-1 reads done before buf 0 reuse
  // merge round 2: wave 2 writes buf 0; wave 0 adds + outputs
  if (e == 2) {
#pragma unroll
    for (int qs = 0; qs < 4; ++qs) {
#pragma unroll
      for (int di = 0; di < 4; ++di)
        *(f32x4*)&mrgO[0][qs][di * 256 + l * 4] = oacc[qs][di];
      mrgL[0][qs][l] = l_i[qs];
    }
  }
  __syncthreads();
  if (e == 0) {
#pragma unroll
    for (int qs = 0; qs < 4; ++qs) {
#pragma unroll
      for (int di = 0; di < 4; ++di)
        oacc[qs][di] += *(const f32x4*)&mrgO[0][qs][di * 256 + l * 4];
      float li = l_i[qs] + mrgL[0][qs][l];
      li += __shfl_xor(li, 16);
      li += __shfl_xor(li, 32);
      const float inv = 1.0f / li;

      const int q = qb * 64 + qs * 16 + ln;
      _Float16* orow = Ob + (size_t)(bidx * S_ + q) * DM + hh * DH + quad * 4;
#pragma unroll
      for (int di = 0; di < 4; ++di) {
        f16x4 o4;
#pragma unroll
        for (int r = 0; r < 4; ++r)
          o4[r] = (_Float16)(oacc[qs][di][r] * inv);
        *(f16x4*)(orow + di * 16) = o4;
      }
    }
  }
}

// ------------------------------- launcher ----------------------------------

extern "C" void kernel_launch(void* const* d_in, const int* in_sizes, int n_in,
                              void* d_out, int out_size, void* d_ws, size_t ws_size,
                              hipStream_t stream) {
  (void)in_sizes; (void)n_in; (void)out_size; (void)ws_size;
  const float* x  = (const float*)d_in[0];
  const float* Wq = (const float*)d_in[1];
  const float* bq = (const float*)d_in[2];
  const float* Wk = (const float*)d_in[3];
  const float* bk = (const float*)d_in[4];
  const float* Wv = (const float*)d_in[5];
  const float* bv = (const float*)d_in[6];
  const float* Wo = (const float*)d_in[7];
  const float* bo = (const float*)d_in[8];

  char* ws = (char*)d_ws;
  _Float16* xb  = (_Float16*)(ws);                      // 8 MB
  _Float16* wb  = (_Float16*)(ws + (8u << 20));         // 4 x 2 MB
  _Float16* qkv = (_Float16*)(ws + (16u << 20));        // QF,KF,VF 8 MB each
  _Float16* ob  = (_Float16*)(ws + (40u << 20));        // 8 MB

  cvt_all_kernel<<<dim3(8192), dim3(256), 0, stream>>>(x, Wq, Wk, Wv, Wo, xb, wb);
  gemm_qkv_kernel<<<dim3(768), dim3(256), 0, stream>>>(xb, wb, bq, bk, bv, qkv);
  attn_kernel<<<dim3(1024), dim3(256), 0, stream>>>(
      qkv, qkv + 4194304, qkv + 2 * 4194304, ob);
  gemm_out_kernel<<<dim3(512), dim3(256), 0, stream>>>(
      ob, wb + (size_t)3 * DM * DM, bo, (float*)d_out);
}